// Round 4
// baseline (444.644 us; speedup 1.0000x reference)
//
#include <hip/hip_runtime.h>
#include <hip/hip_bf16.h>

// Problem constants (reference: B,S,H,D = 2,2048,32,128)
constexpr int Bc = 2;
constexpr int Sc = 2048;
constexpr int Hc = 32;
constexpr int Dc = 128;
constexpr int QKV_STRIDE = 3 * Hc * Dc;   // floats per (b, s) row: 12288

constexpr int BQ = 128;  // query rows per block (8 waves x 16 rows)
constexpr int BK = 64;   // kv rows per tile
// scale (1/sqrt(128)) * log2(e), folded into Q at load; softmax in base-2
constexpr float SCALE_LOG2E = 0.088388347648318f * 1.442695040888963f;
constexpr float DEFER_THR = 8.0f;   // T13: skip rescale while max growth <= 2^8

// LDS strides (shorts). All staging writes / fragment reads verified to hit
// the bank floor: K row 132 (264B), V/P row 68 (136B).
constexpr int KST = 132;
constexpr int VST = 68;
constexpr int PST = 68;

typedef __attribute__((ext_vector_type(8))) short bf16x8;
typedef __attribute__((ext_vector_type(4))) short bf16x4;
typedef __attribute__((ext_vector_type(4))) float f32x4;

static __device__ __forceinline__ short f2bf(float f) {
    // native cast -> compiler pairs these into v_cvt_pk_bf16_f32 (RNE)
    __bf16 h = (__bf16)f;
    return __builtin_bit_cast(short, h);
}

__global__ __launch_bounds__(512)
void attn_fwd(const float* __restrict__ qkv,
              const int* __restrict__ causal_p,
              float* __restrict__ out)
{
    // heavy q-tiles first for better tail behavior under causal imbalance
    const int qt = (int)(gridDim.x - 1) - (int)blockIdx.x;
    const int bh = blockIdx.y;
    const int b = bh >> 5;    // H = 32
    const int h = bh & 31;
    const int causal = *causal_p;

    const int tid  = threadIdx.x;
    const int w    = tid >> 6;    // wave 0..7
    const int lane = tid & 63;
    const int l15  = lane & 15;
    const int lg   = lane >> 4;   // 0..3

    __shared__ short Ks[64 * KST];        // K tile, row-major [k][d]
    __shared__ short Vs[128 * VST];       // V tile, transposed [d][k]
    __shared__ short Ps[8][16 * PST];     // per-wave P re-layout buffer

    const int q0 = qt * BQ;
    const int rowbase = q0 + w * 16;      // this wave's first q row

    // staging decomposition: 16 k-row groups x 32 d-lanes (512 threads)
    const int kg = tid >> 5;   // 0..15 -> k rows kg*4 .. kg*4+3
    const int dl = tid & 31;   // 0..31

    const float* kplane = qkv + (size_t)b * Sc * QKV_STRIDE + Hc * Dc + h * Dc;

    // ---- Q fragments: 16 rows per wave, scaled, bf16 ----
    bf16x8 qf[4];
    {
        const int qrow = q0 + w * 16 + l15;
        const float* qb = qkv + (size_t)(b * Sc + qrow) * QKV_STRIDE + h * Dc;
        #pragma unroll
        for (int dc = 0; dc < 4; ++dc) {
            const float* p = qb + dc * 32 + lg * 8;
            float4 x0 = *(const float4*)(p);
            float4 x1 = *(const float4*)(p + 4);
            bf16x8 q;
            q[0] = f2bf(x0.x * SCALE_LOG2E);
            q[1] = f2bf(x0.y * SCALE_LOG2E);
            q[2] = f2bf(x0.z * SCALE_LOG2E);
            q[3] = f2bf(x0.w * SCALE_LOG2E);
            q[4] = f2bf(x1.x * SCALE_LOG2E);
            q[5] = f2bf(x1.y * SCALE_LOG2E);
            q[6] = f2bf(x1.z * SCALE_LOG2E);
            q[7] = f2bf(x1.w * SCALE_LOG2E);
            qf[dc] = q;
        }
    }

    f32x4 o[8];
    #pragma unroll
    for (int i = 0; i < 8; ++i) o[i] = (f32x4){0.f, 0.f, 0.f, 0.f};
    float mrow[4] = {-1e30f, -1e30f, -1e30f, -1e30f};
    float lrow[4] = {0.f, 0.f, 0.f, 0.f};

    const int nkv = causal ? (2 * qt + 2) : (Sc / BK);

    // ---- staging registers (tile t+1 in flight during compute of t) ----
    float4 kst[4];        // K[kg*4+j][dl*4 .. +3]
    float  vst[4][4];     // V[kg*4+j][q*32 + dl]

    auto issue = [&](int kt) {
        const float* kb = kplane + (size_t)(kt * BK + kg * 4) * QKV_STRIDE;
        #pragma unroll
        for (int j = 0; j < 4; ++j)
            kst[j] = *(const float4*)(kb + (size_t)j * QKV_STRIDE + dl * 4);
        const float* vb = kb + Hc * Dc;
        #pragma unroll
        for (int j = 0; j < 4; ++j) {
            #pragma unroll
            for (int q = 0; q < 4; ++q)
                vst[j][q] = vb[(size_t)j * QKV_STRIDE + q * 32 + dl];
        }
    };

    auto commit = [&]() {
        #pragma unroll
        for (int j = 0; j < 4; ++j) {
            bf16x4 kk;
            kk[0] = f2bf(kst[j].x); kk[1] = f2bf(kst[j].y);
            kk[2] = f2bf(kst[j].z); kk[3] = f2bf(kst[j].w);
            *(bf16x4*)&Ks[(kg * 4 + j) * KST + dl * 4] = kk;
        }
        #pragma unroll
        for (int q = 0; q < 4; ++q) {
            bf16x4 vv;
            #pragma unroll
            for (int j = 0; j < 4; ++j) vv[j] = f2bf(vst[j][q]);
            *(bf16x4*)&Vs[(q * 32 + dl) * VST + kg * 4] = vv;
        }
    };

    issue(0);

    for (int kt = 0; kt < nkv; ++kt) {
        __syncthreads();               // previous tile's LDS readers done
        commit();                      // cvt_pk + conflict-free LDS writes
        if (kt + 1 < nkv) issue(kt + 1);   // next tile's globals fly under compute
        __syncthreads();               // staged tile visible

        const int kbase = kt * BK;
        // wave-uniform causal skip: whole tile above the diagonal for this wave
        if (causal && kbase > rowbase + 15) continue;  // barriers stay aligned

        // ---- S = Q K^T  (4 chunks of 16 keys) ----
        f32x4 s[4];
        __builtin_amdgcn_s_setprio(1);
        #pragma unroll
        for (int kc = 0; kc < 4; ++kc) {
            s[kc] = (f32x4){0.f, 0.f, 0.f, 0.f};
            #pragma unroll
            for (int dc = 0; dc < 4; ++dc) {
                bf16x8 kb = *(const bf16x8*)&Ks[(kc * 16 + l15) * KST + dc * 32 + lg * 8];
                s[kc] = __builtin_amdgcn_mfma_f32_16x16x32_bf16(qf[dc], kb, s[kc], 0, 0, 0);
            }
        }
        __builtin_amdgcn_s_setprio(0);

        // ---- causal mask (only when the tile straddles the diagonal) ----
        if (causal && kbase + BK - 1 > rowbase) {
            #pragma unroll
            for (int kc = 0; kc < 4; ++kc) {
                const int kj = kbase + kc * 16 + l15;
                #pragma unroll
                for (int r = 0; r < 4; ++r) {
                    const int qi = rowbase + lg * 4 + r;
                    if (kj > qi) s[kc][r] = -1e30f;
                }
            }
        }

        // ---- online softmax (base-2), T13 defer-max ----
        float mloc[4];
        #pragma unroll
        for (int r = 0; r < 4; ++r) {
            float m = fmaxf(fmaxf(s[0][r], s[1][r]), fmaxf(s[2][r], s[3][r]));
            #pragma unroll
            for (int off = 1; off < 16; off <<= 1)
                m = fmaxf(m, __shfl_xor(m, off));
            mloc[r] = m;
        }
        const bool grow = (mloc[0] > mrow[0] + DEFER_THR) ||
                          (mloc[1] > mrow[1] + DEFER_THR) ||
                          (mloc[2] > mrow[2] + DEFER_THR) ||
                          (mloc[3] > mrow[3] + DEFER_THR);
        if (__any(grow)) {
            #pragma unroll
            for (int r = 0; r < 4; ++r) {
                const float mnew  = fmaxf(mrow[r], mloc[r]);
                const float alpha = __builtin_amdgcn_exp2f(mrow[r] - mnew);
                mrow[r] = mnew;
                lrow[r] *= alpha;
                #pragma unroll
                for (int dc = 0; dc < 8; ++dc) o[dc][r] *= alpha;
            }
        }
        #pragma unroll
        for (int r = 0; r < 4; ++r) {
            float rsum = 0.f;
            #pragma unroll
            for (int kc = 0; kc < 4; ++kc) {
                const float p = __builtin_amdgcn_exp2f(s[kc][r] - mrow[r]);
                s[kc][r] = p;
                rsum += p;
            }
            #pragma unroll
            for (int off = 1; off < 16; off <<= 1)
                rsum += __shfl_xor(rsum, off);
            lrow[r] += rsum;
        }

        // ---- P -> LDS (per-wave) to re-layout for MFMA A operand ----
        short* pw = Ps[w];
        #pragma unroll
        for (int kc = 0; kc < 4; ++kc) {
            #pragma unroll
            for (int r = 0; r < 4; ++r)
                pw[(lg * 4 + r) * PST + kc * 16 + l15] = f2bf(s[kc][r]);
        }

        // ---- O += P V ----
        __builtin_amdgcn_s_setprio(1);
        #pragma unroll
        for (int k2 = 0; k2 < 2; ++k2) {
            bf16x8 pa = *(const bf16x8*)&pw[l15 * PST + k2 * 32 + lg * 8];
            #pragma unroll
            for (int dc = 0; dc < 8; ++dc) {
                bf16x8 vb = *(const bf16x8*)&Vs[(dc * 16 + l15) * VST + k2 * 32 + lg * 8];
                o[dc] = __builtin_amdgcn_mfma_f32_16x16x32_bf16(pa, vb, o[dc], 0, 0, 0);
            }
        }
        __builtin_amdgcn_s_setprio(0);
    }

    // ---- epilogue: normalize + store fp32 ----
    float inv[4];
    #pragma unroll
    for (int r = 0; r < 4; ++r) inv[r] = 1.f / lrow[r];
    #pragma unroll
    for (int r = 0; r < 4; ++r) {
        const int qg = q0 + w * 16 + lg * 4 + r;
        float* ob = out + (size_t)(b * Sc + qg) * (Hc * Dc) + h * Dc;
        #pragma unroll
        for (int dc = 0; dc < 8; ++dc)
            ob[dc * 16 + l15] = o[dc][r] * inv[r];
    }
}

extern "C" void kernel_launch(void* const* d_in, const int* in_sizes, int n_in,
                              void* d_out, int out_size, void* d_ws, size_t ws_size,
                              hipStream_t stream) {
    const float* qkv = (const float*)d_in[0];
    const int* causal = (const int*)d_in[1];
    float* out = (float*)d_out;
    dim3 grid(Sc / BQ, Bc * Hc);
    attn_fwd<<<grid, 512, 0, stream>>>(qkv, causal, out);
}

// Round 5
// 434.886 us; speedup vs baseline: 1.0224x; 1.0224x over previous
//
#include <hip/hip_runtime.h>
#include <hip/hip_bf16.h>

// Problem constants (reference: B,S,H,D = 2,2048,32,128)
constexpr int Bc = 2;
constexpr int Sc = 2048;
constexpr int Hc = 32;
constexpr int Dc = 128;
constexpr int QKV_STRIDE = 3 * Hc * Dc;   // floats per (b, s) row: 12288

constexpr int BQ = 64;   // query rows per block (4 waves x 16 rows)
constexpr int BK = 64;   // kv rows per tile
// scale (1/sqrt(128)) * log2(e), folded into Q at load; softmax in base-2
constexpr float SCALE_LOG2E = 0.088388347648318f * 1.442695040888963f;
constexpr float DEFER_THR = 8.0f;   // T13: skip rescale while max growth <= 2^8

// LDS strides (shorts) — measured conflict-free in round 4 (SQ_LDS_BANK_CONFLICT = 0):
// K row 132 (264B), V/P row 68 (136B).
constexpr int KST = 132;
constexpr int VST = 68;
constexpr int PST = 68;

typedef __attribute__((ext_vector_type(8))) short bf16x8;
typedef __attribute__((ext_vector_type(4))) short bf16x4;
typedef __attribute__((ext_vector_type(4))) float f32x4;

static __device__ __forceinline__ short f2bf(float f) {
    // native cast -> compiler pairs these into v_cvt_pk_bf16_f32 (RNE)
    __bf16 h = (__bf16)f;
    return __builtin_bit_cast(short, h);
}

// Raw barrier: does NOT drain vmcnt (unlike __syncthreads), so global loads
// issued for the next tile stay in flight across it (T4 counted-vmcnt idea:
// the consuming commit()'s register deps provide the wait). LDS visibility is
// guaranteed by the explicit lgkmcnt(0) before the barrier.
static __device__ __forceinline__ void lds_barrier() {
    asm volatile("s_waitcnt lgkmcnt(0)" ::: "memory");
    __builtin_amdgcn_s_barrier();
    asm volatile("" ::: "memory");
}

__global__ __launch_bounds__(256)
void attn_fwd(const float* __restrict__ qkv,
              const int* __restrict__ causal_p,
              float* __restrict__ out)
{
    // heavy q-tiles first for better tail behavior under causal imbalance
    const int qt = (int)(gridDim.x - 1) - (int)blockIdx.x;
    const int bh = blockIdx.y;
    const int b = bh >> 5;    // H = 32
    const int h = bh & 31;
    const int causal = *causal_p;

    const int tid  = threadIdx.x;
    const int w    = tid >> 6;    // wave 0..3
    const int lane = tid & 63;
    const int l15  = lane & 15;
    const int lg   = lane >> 4;   // 0..3

    __shared__ short Ks[64 * KST];        // K tile, row-major [k][d]
    __shared__ short Vs[128 * VST];       // V tile, transposed [d][k]
    __shared__ short Ps[4][16 * PST];     // per-wave P re-layout buffer

    const int q0 = qt * BQ;

    // staging decomposition: 8 k-row groups x 32 d-lanes
    const int kg = tid >> 5;   // 0..7 -> k rows kg*8 .. kg*8+7
    const int dl = tid & 31;   // 0..31

    const float* kplane = qkv + (size_t)b * Sc * QKV_STRIDE + Hc * Dc + h * Dc;

    // ---- Q fragments: 16 rows per wave, scaled, bf16 ----
    bf16x8 qf[4];
    {
        const int qrow = q0 + w * 16 + l15;
        const float* qb = qkv + (size_t)(b * Sc + qrow) * QKV_STRIDE + h * Dc;
        #pragma unroll
        for (int dc = 0; dc < 4; ++dc) {
            const float* p = qb + dc * 32 + lg * 8;
            float4 x0 = *(const float4*)(p);
            float4 x1 = *(const float4*)(p + 4);
            bf16x8 q;
            q[0] = f2bf(x0.x * SCALE_LOG2E);
            q[1] = f2bf(x0.y * SCALE_LOG2E);
            q[2] = f2bf(x0.z * SCALE_LOG2E);
            q[3] = f2bf(x0.w * SCALE_LOG2E);
            q[4] = f2bf(x1.x * SCALE_LOG2E);
            q[5] = f2bf(x1.y * SCALE_LOG2E);
            q[6] = f2bf(x1.z * SCALE_LOG2E);
            q[7] = f2bf(x1.w * SCALE_LOG2E);
            qf[dc] = q;
        }
    }

    f32x4 o[8];
    #pragma unroll
    for (int i = 0; i < 8; ++i) o[i] = (f32x4){0.f, 0.f, 0.f, 0.f};
    float mrow[4] = {-1e30f, -1e30f, -1e30f, -1e30f};
    float lrow[4] = {0.f, 0.f, 0.f, 0.f};

    const int nkv = causal ? (qt + 1) : (Sc / BK);

    // ---- staging registers (tile t+1 in flight during compute of t) ----
    float4 kst[8];        // K[kg*8+j][dl*4 .. +3]
    float  vst[8][4];     // V[kg*8+j][q*32 + dl]

    auto issue = [&](int kt) {
        const float* kb = kplane + (size_t)(kt * BK + kg * 8) * QKV_STRIDE;
        #pragma unroll
        for (int j = 0; j < 8; ++j)
            kst[j] = *(const float4*)(kb + (size_t)j * QKV_STRIDE + dl * 4);
        const float* vb = kb + Hc * Dc;
        #pragma unroll
        for (int j = 0; j < 8; ++j) {
            #pragma unroll
            for (int q = 0; q < 4; ++q)
                vst[j][q] = vb[(size_t)j * QKV_STRIDE + q * 32 + dl];
        }
    };

    auto commit = [&]() {
        #pragma unroll
        for (int j = 0; j < 8; ++j) {
            bf16x4 kk;
            kk[0] = f2bf(kst[j].x); kk[1] = f2bf(kst[j].y);
            kk[2] = f2bf(kst[j].z); kk[3] = f2bf(kst[j].w);
            *(bf16x4*)&Ks[(kg * 8 + j) * KST + dl * 4] = kk;
        }
        #pragma unroll
        for (int q = 0; q < 4; ++q) {
            bf16x8 vv;
            #pragma unroll
            for (int j = 0; j < 8; ++j) vv[j] = f2bf(vst[j][q]);
            *(bf16x8*)&Vs[(q * 32 + dl) * VST + kg * 8] = vv;
        }
    };

    issue(0);

    for (int kt = 0; kt < nkv; ++kt) {
        lds_barrier();                 // previous tile's LDS readers done
        commit();                      // vmcnt reg-dep wait + cvt_pk + LDS writes
        if (kt + 1 < nkv) issue(kt + 1);   // in flight across the raw barrier
        lds_barrier();                 // staged tile visible (lgkm only, no vmcnt drain)

        // ---- S = Q K^T  (4 chunks of 16 keys) ----
        f32x4 s[4];
        __builtin_amdgcn_s_setprio(1);
        #pragma unroll
        for (int kc = 0; kc < 4; ++kc) {
            s[kc] = (f32x4){0.f, 0.f, 0.f, 0.f};
            #pragma unroll
            for (int dc = 0; dc < 4; ++dc) {
                bf16x8 kb = *(const bf16x8*)&Ks[(kc * 16 + l15) * KST + dc * 32 + lg * 8];
                s[kc] = __builtin_amdgcn_mfma_f32_16x16x32_bf16(qf[dc], kb, s[kc], 0, 0, 0);
            }
        }
        __builtin_amdgcn_s_setprio(0);

        // ---- causal mask on the diagonal tile ----
        if (causal && kt == qt) {
            #pragma unroll
            for (int kc = 0; kc < 4; ++kc) {
                const int kj = kc * 16 + l15;
                #pragma unroll
                for (int r = 0; r < 4; ++r) {
                    const int qi = w * 16 + lg * 4 + r;
                    if (kj > qi) s[kc][r] = -1e30f;
                }
            }
        }

        // ---- online softmax (base-2), T13 defer-max ----
        float mloc[4];
        #pragma unroll
        for (int r = 0; r < 4; ++r) {
            float m = fmaxf(fmaxf(s[0][r], s[1][r]), fmaxf(s[2][r], s[3][r]));
            #pragma unroll
            for (int off = 1; off < 16; off <<= 1)
                m = fmaxf(m, __shfl_xor(m, off));
            mloc[r] = m;
        }
        const bool grow = (mloc[0] > mrow[0] + DEFER_THR) ||
                          (mloc[1] > mrow[1] + DEFER_THR) ||
                          (mloc[2] > mrow[2] + DEFER_THR) ||
                          (mloc[3] > mrow[3] + DEFER_THR);
        if (__any(grow)) {
            #pragma unroll
            for (int r = 0; r < 4; ++r) {
                const float mnew  = fmaxf(mrow[r], mloc[r]);
                const float alpha = __builtin_amdgcn_exp2f(mrow[r] - mnew);
                mrow[r] = mnew;
                lrow[r] *= alpha;
                #pragma unroll
                for (int dc = 0; dc < 8; ++dc) o[dc][r] *= alpha;
            }
        }
        #pragma unroll
        for (int r = 0; r < 4; ++r) {
            float rsum = 0.f;
            #pragma unroll
            for (int kc = 0; kc < 4; ++kc) {
                const float p = __builtin_amdgcn_exp2f(s[kc][r] - mrow[r]);
                s[kc][r] = p;
                rsum += p;
            }
            #pragma unroll
            for (int off = 1; off < 16; off <<= 1)
                rsum += __shfl_xor(rsum, off);
            lrow[r] += rsum;
        }

        // ---- P -> LDS (per-wave) to re-layout for MFMA A operand ----
        short* pw = Ps[w];
        #pragma unroll
        for (int kc = 0; kc < 4; ++kc) {
            #pragma unroll
            for (int r = 0; r < 4; ++r)
                pw[(lg * 4 + r) * PST + kc * 16 + l15] = f2bf(s[kc][r]);
        }

        // ---- O += P V ----
        __builtin_amdgcn_s_setprio(1);
        #pragma unroll
        for (int k2 = 0; k2 < 2; ++k2) {
            bf16x8 pa = *(const bf16x8*)&pw[l15 * PST + k2 * 32 + lg * 8];
            #pragma unroll
            for (int dc = 0; dc < 8; ++dc) {
                bf16x8 vb = *(const bf16x8*)&Vs[(dc * 16 + l15) * VST + k2 * 32 + lg * 8];
                o[dc] = __builtin_amdgcn_mfma_f32_16x16x32_bf16(pa, vb, o[dc], 0, 0, 0);
            }
        }
        __builtin_amdgcn_s_setprio(0);
    }

    // ---- epilogue: normalize + store fp32 ----
    float inv[4];
    #pragma unroll
    for (int r = 0; r < 4; ++r) inv[r] = 1.f / lrow[r];
    #pragma unroll
    for (int r = 0; r < 4; ++r) {
        const int qg = q0 + w * 16 + lg * 4 + r;
        float* ob = out + (size_t)(b * Sc + qg) * (Hc * Dc) + h * Dc;
        #pragma unroll
        for (int dc = 0; dc < 8; ++dc)
            ob[dc * 16 + l15] = o[dc][r] * inv[r];
    }
}

extern "C" void kernel_launch(void* const* d_in, const int* in_sizes, int n_in,
                              void* d_out, int out_size, void* d_ws, size_t ws_size,
                              hipStream_t stream) {
    const float* qkv = (const float*)d_in[0];
    const int* causal = (const int*)d_in[1];
    float* out = (float*)d_out;
    dim3 grid(Sc / BQ, Bc * Hc);
    attn_fwd<<<grid, 256, 0, stream>>>(qkv, causal, out);
}

// Round 6
// 320.118 us; speedup vs baseline: 1.3890x; 1.3585x over previous
//
#include <hip/hip_runtime.h>
#include <hip/hip_bf16.h>

// Problem constants (reference: B,S,H,D = 2,2048,32,128)
constexpr int Bc = 2;
constexpr int Sc = 2048;
constexpr int Hc = 32;
constexpr int Dc = 128;
constexpr int QKV_STRIDE = 3 * Hc * Dc;   // floats per (b, s) row: 12288

constexpr int BQ = 128;  // query rows per block (4 waves x 32 rows)
constexpr int BK = 64;   // kv rows per tile
// scale (1/sqrt(128)) * log2(e), folded into Q at load; softmax in base-2
constexpr float SCALE_LOG2E = 0.088388347648318f * 1.442695040888963f;
constexpr float DEFER_THR = 8.0f;   // T13

// LDS strides (shorts) — measured conflict-free (r4/r5: SQ_LDS_BANK_CONFLICT = 0)
constexpr int KST = 132;   // K row 264B
constexpr int VST = 68;    // V row 136B

typedef __attribute__((ext_vector_type(8)))  short    bf16x8;
typedef __attribute__((ext_vector_type(4)))  short    bf16x4;
typedef __attribute__((ext_vector_type(16))) float    f32x16;
typedef __attribute__((ext_vector_type(4)))  unsigned u32x4;

static __device__ __forceinline__ short f2bf(float f) {
    __bf16 h = (__bf16)f;                  // RNE; compiler pairs into v_cvt_pk_bf16_f32
    return __builtin_bit_cast(short, h);
}
static __device__ __forceinline__ unsigned pk2(float lo, float hi) {
    union { short2 s; unsigned u; } x;
    x.s.x = f2bf(lo); x.s.y = f2bf(hi);
    return x.u;
}
// Raw barrier (lgkm drain only) — next-tile global loads stay in flight across it.
static __device__ __forceinline__ void lds_barrier() {
    asm volatile("s_waitcnt lgkmcnt(0)" ::: "memory");
    __builtin_amdgcn_s_barrier();
    asm volatile("" ::: "memory");
}

__global__ __launch_bounds__(256)
void attn_fwd(const float* __restrict__ qkv,
              const int* __restrict__ causal_p,
              float* __restrict__ out)
{
    const int qt = (int)(gridDim.x - 1) - (int)blockIdx.x;   // heavy-first
    const int bh = blockIdx.y;
    const int b = bh >> 5;    // H = 32
    const int h = bh & 31;
    const int causal = *causal_p;

    const int tid  = threadIdx.x;
    const int w    = tid >> 6;     // wave 0..3, owns 32 q rows
    const int lane = tid & 63;
    const int l31  = lane & 31;
    const int hf   = lane >> 5;    // half 0/1

    __shared__ short Ks[64 * KST];    // K tile [k][d]
    __shared__ short Vs[128 * VST];   // V tile transposed [d][k]

    const int q0  = qt * BQ;
    const int wq0 = q0 + w * 32;      // wave's first global q row

    // staging decomposition: 8 k-row groups x 32 d-lanes
    const int kg = tid >> 5;   // 0..7 -> k rows kg*8 .. kg*8+7
    const int dl = tid & 31;

    const float* kplane = qkv + (size_t)b * Sc * QKV_STRIDE + Hc * Dc + h * Dc;

    // ---- Q as swapped-QK B-fragments: lane holds q = l31, dh = step*16 + hf*8 + j ----
    bf16x8 qf[8];
    {
        const float* qb = qkv + (size_t)(b * Sc + wq0 + l31) * QKV_STRIDE + h * Dc;
        #pragma unroll
        for (int st = 0; st < 8; ++st) {
            const float* p = qb + st * 16 + hf * 8;
            float4 x0 = *(const float4*)(p);
            float4 x1 = *(const float4*)(p + 4);
            bf16x8 q;
            q[0] = f2bf(x0.x * SCALE_LOG2E);
            q[1] = f2bf(x0.y * SCALE_LOG2E);
            q[2] = f2bf(x0.z * SCALE_LOG2E);
            q[3] = f2bf(x0.w * SCALE_LOG2E);
            q[4] = f2bf(x1.x * SCALE_LOG2E);
            q[5] = f2bf(x1.y * SCALE_LOG2E);
            q[6] = f2bf(x1.z * SCALE_LOG2E);
            q[7] = f2bf(x1.w * SCALE_LOG2E);
            qf[st] = q;
        }
    }

    f32x16 o[4];
    #pragma unroll
    for (int db = 0; db < 4; ++db)
        #pragma unroll
        for (int i = 0; i < 16; ++i) o[db][i] = 0.f;
    float m = -1e30f, l = 0.f;

    const int nkv = causal ? (2 * qt + 2) : (Sc / BK);

    // ---- staging registers (tile t+1 in flight during compute of t) ----
    float4 kst[8];
    float  vst[8][4];

    auto issue = [&](int kt) {
        const float* kb = kplane + (size_t)(kt * BK + kg * 8) * QKV_STRIDE;
        #pragma unroll
        for (int j = 0; j < 8; ++j)
            kst[j] = *(const float4*)(kb + (size_t)j * QKV_STRIDE + dl * 4);
        const float* vb = kb + Hc * Dc;
        #pragma unroll
        for (int j = 0; j < 8; ++j) {
            #pragma unroll
            for (int q = 0; q < 4; ++q)
                vst[j][q] = vb[(size_t)j * QKV_STRIDE + q * 32 + dl];
        }
    };

    auto commit = [&]() {
        #pragma unroll
        for (int j = 0; j < 8; ++j) {
            bf16x4 kk;
            kk[0] = f2bf(kst[j].x); kk[1] = f2bf(kst[j].y);
            kk[2] = f2bf(kst[j].z); kk[3] = f2bf(kst[j].w);
            *(bf16x4*)&Ks[(kg * 8 + j) * KST + dl * 4] = kk;
        }
        #pragma unroll
        for (int q = 0; q < 4; ++q) {
            bf16x8 vv;
            #pragma unroll
            for (int j = 0; j < 8; ++j) vv[j] = f2bf(vst[j][q]);
            *(bf16x8*)&Vs[(q * 32 + dl) * VST + kg * 8] = vv;
        }
    };

    issue(0);

    for (int kt = 0; kt < nkv; ++kt) {
        lds_barrier();                      // prev tile's readers done
        commit();
        if (kt + 1 < nkv) issue(kt + 1);    // flies across the raw barrier
        lds_barrier();                      // staged tile visible

        const int kbase = kt * BK;
        if (causal && kbase > wq0 + 31) continue;   // wave-uniform skip

        // ---- S^T = K Q^T : lane holds S[q=l31][32 k's per mb via C-layout] ----
        f32x16 acc[2];
        #pragma unroll
        for (int mb = 0; mb < 2; ++mb)
            #pragma unroll
            for (int i = 0; i < 16; ++i) acc[mb][i] = 0.f;
        __builtin_amdgcn_s_setprio(1);
        #pragma unroll
        for (int st = 0; st < 8; ++st) {
            #pragma unroll
            for (int mb = 0; mb < 2; ++mb) {
                bf16x8 ka = *(const bf16x8*)&Ks[(mb * 32 + l31) * KST + st * 16 + hf * 8];
                acc[mb] = __builtin_amdgcn_mfma_f32_32x32x16_bf16(ka, qf[st], acc[mb], 0, 0, 0);
            }
        }
        __builtin_amdgcn_s_setprio(0);

        // ---- causal mask (straddle tiles only); k = kbase+mb*32+rowpat(reg,hf) ----
        if (causal && kbase + 63 > wq0) {
            const int qg = wq0 + l31;
            #pragma unroll
            for (int mb = 0; mb < 2; ++mb) {
                #pragma unroll
                for (int r = 0; r < 16; ++r) {
                    const int kgl = kbase + mb * 32 + (r & 3) + 8 * (r >> 2) + 4 * hf;
                    if (kgl > qg) acc[mb][r] = -1e30f;
                }
            }
        }

        // ---- online softmax: fully in-lane + one half-swap; T13 defer ----
        float pm = acc[0][0];
        #pragma unroll
        for (int i = 1; i < 16; ++i) pm = fmaxf(pm, acc[0][i]);
        #pragma unroll
        for (int i = 0; i < 16; ++i) pm = fmaxf(pm, acc[1][i]);
        pm = fmaxf(pm, __shfl_xor(pm, 32));
        if (__any(pm > m + DEFER_THR)) {
            const float mnew  = fmaxf(m, pm);
            const float alpha = __builtin_amdgcn_exp2f(m - mnew);
            m = mnew; l *= alpha;
            #pragma unroll
            for (int r = 0; r < 16; ++r) {
                const float ar = __shfl(alpha, (r & 3) + 8 * (r >> 2) + 4 * hf);
                o[0][r] *= ar; o[1][r] *= ar; o[2][r] *= ar; o[3][r] *= ar;
            }
        }
        float rs = 0.f;
        #pragma unroll
        for (int i = 0; i < 16; ++i) {
            const float p = __builtin_amdgcn_exp2f(acc[0][i] - m);
            acc[0][i] = p; rs += p;
        }
        #pragma unroll
        for (int i = 0; i < 16; ++i) {
            const float p = __builtin_amdgcn_exp2f(acc[1][i] - m);
            acc[1][i] = p; rs += p;
        }
        rs += __shfl_xor(rs, 32);
        l += rs;

        // ---- P -> bf16 A-fragments in-register (16 cvt_pk + 8 half-exchanges) ----
        // group (mb,c): rows 4c..4c+3 of acc[mb]; w0=(r0,r1) w1=(r2,r3)
        unsigned wpk[2][4][2];
        #pragma unroll
        for (int mb = 0; mb < 2; ++mb)
            #pragma unroll
            for (int c = 0; c < 4; ++c) {
                wpk[mb][c][0] = pk2(acc[mb][4 * c + 0], acc[mb][4 * c + 1]);
                wpk[mb][c][1] = pk2(acc[mb][4 * c + 2], acc[mb][4 * c + 3]);
            }
        // h=0 lanes receive other-half even-c groups, h=1 receive odd-c
        unsigned cross[2][2][2];
        #pragma unroll
        for (int mb = 0; mb < 2; ++mb)
            #pragma unroll
            for (int ci = 0; ci < 2; ++ci)
                #pragma unroll
                for (int wd = 0; wd < 2; ++wd) {
                    const unsigned send = hf ? wpk[mb][2 * ci][wd] : wpk[mb][2 * ci + 1][wd];
                    cross[mb][ci][wd] = (unsigned)__shfl_xor((int)send, 32);
                }
        // pa[ks][j] = P[q][ks*16 + hf*8 + j]
        bf16x8 pa[4];
        #pragma unroll
        for (int ks = 0; ks < 4; ++ks) {
            const int mb = ks >> 1, ci = ks & 1;
            u32x4 wv;
            wv[0] = hf ? cross[mb][ci][0] : wpk[mb][2 * ci][0];
            wv[1] = hf ? cross[mb][ci][1] : wpk[mb][2 * ci][1];
            wv[2] = hf ? wpk[mb][2 * ci + 1][0] : cross[mb][ci][0];
            wv[3] = hf ? wpk[mb][2 * ci + 1][1] : cross[mb][ci][1];
            pa[ks] = __builtin_bit_cast(bf16x8, wv);
        }

        // ---- O += P V  (4 independent accumulator chains) ----
        __builtin_amdgcn_s_setprio(1);
        #pragma unroll
        for (int ks = 0; ks < 4; ++ks) {
            #pragma unroll
            for (int db = 0; db < 4; ++db) {
                bf16x8 vb = *(const bf16x8*)&Vs[(db * 32 + l31) * VST + ks * 16 + hf * 8];
                o[db] = __builtin_amdgcn_mfma_f32_32x32x16_bf16(pa[ks], vb, o[db], 0, 0, 0);
            }
        }
        __builtin_amdgcn_s_setprio(0);
    }

    // ---- epilogue: per-row 1/l gather + fp32 store (lanes contiguous in d) ----
    #pragma unroll
    for (int r = 0; r < 16; ++r) {
        const int rq = (r & 3) + 8 * (r >> 2) + 4 * hf;
        const float lr = __shfl(l, rq);
        const float inv = 1.f / lr;
        const int qg = wq0 + rq;
        float* ob = out + (size_t)(b * Sc + qg) * (Hc * Dc) + h * Dc + l31;
        ob[0]  = o[0][r] * inv;
        ob[32] = o[1][r] * inv;
        ob[64] = o[2][r] * inv;
        ob[96] = o[3][r] * inv;
    }
}

extern "C" void kernel_launch(void* const* d_in, const int* in_sizes, int n_in,
                              void* d_out, int out_size, void* d_ws, size_t ws_size,
                              hipStream_t stream) {
    const float* qkv = (const float*)d_in[0];
    const int* causal = (const int*)d_in[1];
    float* out = (float*)d_out;
    dim3 grid(Sc / BQ, Bc * Hc);
    attn_fwd<<<grid, 256, 0, stream>>>(qkv, causal, out);
}

// Round 7
// 200.575 us; speedup vs baseline: 2.2168x; 1.5960x over previous
//
#include <hip/hip_runtime.h>
#include <hip/hip_bf16.h>

// Problem constants (reference: B,S,H,D = 2,2048,32,128)
constexpr int Bc = 2;
constexpr int Sc = 2048;
constexpr int Hc = 32;
constexpr int Dc = 128;
constexpr int QKV_STRIDE = 3 * Hc * Dc;   // floats per (b, s) row: 12288

constexpr int BQ = 128;  // query rows per block (4 waves x 32 rows)
constexpr int BK = 64;   // kv rows per tile
// scale (1/sqrt(128)) * log2(e), folded into Q at load; softmax in base-2
constexpr float SCALE_LOG2E = 0.088388347648318f * 1.442695040888963f;
constexpr float DEFER_THR = 8.0f;   // T13

// LDS strides (shorts) — measured conflict-free (r4-r6: SQ_LDS_BANK_CONFLICT = 0)
constexpr int KST = 132;   // K row 264B
constexpr int VST = 68;    // V row 136B

typedef __attribute__((ext_vector_type(8)))  short    bf16x8;
typedef __attribute__((ext_vector_type(4)))  short    bf16x4;
typedef __attribute__((ext_vector_type(16))) float    f32x16;
typedef __attribute__((ext_vector_type(4)))  unsigned u32x4;

static __device__ __forceinline__ short f2bf(float f) {
    __bf16 h = (__bf16)f;                  // RNE; compiler pairs into v_cvt_pk_bf16_f32
    return __builtin_bit_cast(short, h);
}
static __device__ __forceinline__ unsigned pk2(float lo, float hi) {
    union { short2 s; unsigned u; } x;
    x.s.x = f2bf(lo); x.s.y = f2bf(hi);
    return x.u;
}
// Raw barrier (lgkm drain only) — next-tile global loads stay in flight across it.
static __device__ __forceinline__ void lds_barrier() {
    asm volatile("s_waitcnt lgkmcnt(0)" ::: "memory");
    __builtin_amdgcn_s_barrier();
    asm volatile("" ::: "memory");
}

__global__ __launch_bounds__(256)
void attn_fwd(const float* __restrict__ qkv,
              const int* __restrict__ causal_p,
              float* __restrict__ out)
{
    // Work-balanced 1D grid: bid = o*64 + bh. Map o -> qt so that the qt sets
    // co-landing on one CU under stride-256 round-robin ({o, o+4, o+8, o+12})
    // have equal total causal work: {15,14,1,0},{13,12,3,2},{11,10,5,4},{9,8,7,6}.
    // Heavy classes dispatch first (o=0 -> qt=15); queued-last blocks are light.
    const int bid = blockIdx.x;
    const int o   = bid >> 6;
    const int bh  = bid & 63;
    const int r_  = o & 3;
    const int j_  = o >> 2;
    const int bq_ = 15 - 2 * r_;
    const int qt  = (j_ < 2) ? (bq_ - j_) : (15 - bq_ + 3 - j_);

    const int b = bh >> 5;    // H = 32
    const int h = bh & 31;
    const int causal = *causal_p;

    const int tid  = threadIdx.x;
    const int w    = tid >> 6;     // wave 0..3, owns 32 q rows
    const int lane = tid & 63;
    const int l31  = lane & 31;
    const int hf   = lane >> 5;    // half 0/1

    __shared__ short Ks[64 * KST];    // K tile [k][d]
    __shared__ short Vs[128 * VST];   // V tile transposed [d][k]

    const int q0  = qt * BQ;
    const int wq0 = q0 + w * 32;      // wave's first global q row

    // staging decomposition: 8 k-row groups x 32 d-lanes
    const int kg = tid >> 5;   // 0..7 -> k rows kg*8 .. kg*8+7
    const int dl = tid & 31;

    const float* kplane = qkv + (size_t)b * Sc * QKV_STRIDE + Hc * Dc + h * Dc;

    // ---- Q as swapped-QK B-fragments: lane holds q = l31, dh = step*16 + hf*8 + j ----
    bf16x8 qf[8];
    {
        const float* qb = qkv + (size_t)(b * Sc + wq0 + l31) * QKV_STRIDE + h * Dc;
        #pragma unroll
        for (int st = 0; st < 8; ++st) {
            const float* p = qb + st * 16 + hf * 8;
            float4 x0 = *(const float4*)(p);
            float4 x1 = *(const float4*)(p + 4);
            bf16x8 q;
            q[0] = f2bf(x0.x * SCALE_LOG2E);
            q[1] = f2bf(x0.y * SCALE_LOG2E);
            q[2] = f2bf(x0.z * SCALE_LOG2E);
            q[3] = f2bf(x0.w * SCALE_LOG2E);
            q[4] = f2bf(x1.x * SCALE_LOG2E);
            q[5] = f2bf(x1.y * SCALE_LOG2E);
            q[6] = f2bf(x1.z * SCALE_LOG2E);
            q[7] = f2bf(x1.w * SCALE_LOG2E);
            qf[st] = q;
        }
    }

    f32x16 o_[4];
    #pragma unroll
    for (int db = 0; db < 4; ++db)
        #pragma unroll
        for (int i = 0; i < 16; ++i) o_[db][i] = 0.f;
    float m = -1e30f, l = 0.f;

    const int nkv = causal ? (2 * qt + 2) : (Sc / BK);

    // ---- staging registers (tile t+1 in flight during compute of t) ----
    float4 kst[8];
    float  vst[8][4];

    auto issue = [&](int kt) {
        const float* kb = kplane + (size_t)(kt * BK + kg * 8) * QKV_STRIDE;
        #pragma unroll
        for (int j = 0; j < 8; ++j)
            kst[j] = *(const float4*)(kb + (size_t)j * QKV_STRIDE + dl * 4);
        const float* vb = kb + Hc * Dc;
        #pragma unroll
        for (int j = 0; j < 8; ++j) {
            #pragma unroll
            for (int q = 0; q < 4; ++q)
                vst[j][q] = vb[(size_t)j * QKV_STRIDE + q * 32 + dl];
        }
    };

    auto commit = [&]() {
        #pragma unroll
        for (int j = 0; j < 8; ++j) {
            bf16x4 kk;
            kk[0] = f2bf(kst[j].x); kk[1] = f2bf(kst[j].y);
            kk[2] = f2bf(kst[j].z); kk[3] = f2bf(kst[j].w);
            *(bf16x4*)&Ks[(kg * 8 + j) * KST + dl * 4] = kk;
        }
        #pragma unroll
        for (int q = 0; q < 4; ++q) {
            bf16x8 vv;
            #pragma unroll
            for (int j = 0; j < 8; ++j) vv[j] = f2bf(vst[j][q]);
            *(bf16x8*)&Vs[(q * 32 + dl) * VST + kg * 8] = vv;
        }
    };

    issue(0);

    for (int kt = 0; kt < nkv; ++kt) {
        lds_barrier();                      // prev tile's readers done
        commit();
        if (kt + 1 < nkv) issue(kt + 1);    // flies across the raw barrier
        lds_barrier();                      // staged tile visible

        const int kbase = kt * BK;
        if (causal && kbase > wq0 + 31) continue;   // wave-uniform skip

        // ---- S^T = K Q^T : lane holds S[q=l31][32 k's per mb via C-layout] ----
        f32x16 acc[2];
        #pragma unroll
        for (int mb = 0; mb < 2; ++mb)
            #pragma unroll
            for (int i = 0; i < 16; ++i) acc[mb][i] = 0.f;
        __builtin_amdgcn_s_setprio(1);
        #pragma unroll
        for (int st = 0; st < 8; ++st) {
            #pragma unroll
            for (int mb = 0; mb < 2; ++mb) {
                bf16x8 ka = *(const bf16x8*)&Ks[(mb * 32 + l31) * KST + st * 16 + hf * 8];
                acc[mb] = __builtin_amdgcn_mfma_f32_32x32x16_bf16(ka, qf[st], acc[mb], 0, 0, 0);
            }
        }
        __builtin_amdgcn_s_setprio(0);

        // ---- causal mask (straddle tiles only); k = kbase+mb*32+rowpat(reg,hf) ----
        if (causal && kbase + 63 > wq0) {
            const int qg = wq0 + l31;
            #pragma unroll
            for (int mb = 0; mb < 2; ++mb) {
                #pragma unroll
                for (int r = 0; r < 16; ++r) {
                    const int kgl = kbase + mb * 32 + (r & 3) + 8 * (r >> 2) + 4 * hf;
                    if (kgl > qg) acc[mb][r] = -1e30f;
                }
            }
        }

        // ---- online softmax: fully in-lane + one half-swap; T13 defer ----
        float pm = acc[0][0];
        #pragma unroll
        for (int i = 1; i < 16; ++i) pm = fmaxf(pm, acc[0][i]);
        #pragma unroll
        for (int i = 0; i < 16; ++i) pm = fmaxf(pm, acc[1][i]);
        pm = fmaxf(pm, __shfl_xor(pm, 32));
        if (__any(pm > m + DEFER_THR)) {
            const float mnew  = fmaxf(m, pm);
            const float alpha = __builtin_amdgcn_exp2f(m - mnew);
            m = mnew; l *= alpha;
            #pragma unroll
            for (int r = 0; r < 16; ++r) {
                const float ar = __shfl(alpha, (r & 3) + 8 * (r >> 2) + 4 * hf);
                o_[0][r] *= ar; o_[1][r] *= ar; o_[2][r] *= ar; o_[3][r] *= ar;
            }
        }
        float rs = 0.f;
        #pragma unroll
        for (int i = 0; i < 16; ++i) {
            const float p = __builtin_amdgcn_exp2f(acc[0][i] - m);
            acc[0][i] = p; rs += p;
        }
        #pragma unroll
        for (int i = 0; i < 16; ++i) {
            const float p = __builtin_amdgcn_exp2f(acc[1][i] - m);
            acc[1][i] = p; rs += p;
        }
        rs += __shfl_xor(rs, 32);
        l += rs;

        // ---- P -> bf16 A-fragments in-register (16 cvt_pk + 8 half-exchanges) ----
        unsigned wpk[2][4][2];
        #pragma unroll
        for (int mb = 0; mb < 2; ++mb)
            #pragma unroll
            for (int c = 0; c < 4; ++c) {
                wpk[mb][c][0] = pk2(acc[mb][4 * c + 0], acc[mb][4 * c + 1]);
                wpk[mb][c][1] = pk2(acc[mb][4 * c + 2], acc[mb][4 * c + 3]);
            }
        unsigned cross[2][2][2];
        #pragma unroll
        for (int mb = 0; mb < 2; ++mb)
            #pragma unroll
            for (int ci = 0; ci < 2; ++ci)
                #pragma unroll
                for (int wd = 0; wd < 2; ++wd) {
                    const unsigned send = hf ? wpk[mb][2 * ci][wd] : wpk[mb][2 * ci + 1][wd];
                    cross[mb][ci][wd] = (unsigned)__shfl_xor((int)send, 32);
                }
        bf16x8 pa[4];
        #pragma unroll
        for (int ks = 0; ks < 4; ++ks) {
            const int mb = ks >> 1, ci = ks & 1;
            u32x4 wv;
            wv[0] = hf ? cross[mb][ci][0] : wpk[mb][2 * ci][0];
            wv[1] = hf ? cross[mb][ci][1] : wpk[mb][2 * ci][1];
            wv[2] = hf ? wpk[mb][2 * ci + 1][0] : cross[mb][ci][0];
            wv[3] = hf ? wpk[mb][2 * ci + 1][1] : cross[mb][ci][1];
            pa[ks] = __builtin_bit_cast(bf16x8, wv);
        }

        // ---- O += P V  (4 independent accumulator chains) ----
        __builtin_amdgcn_s_setprio(1);
        #pragma unroll
        for (int ks = 0; ks < 4; ++ks) {
            #pragma unroll
            for (int db = 0; db < 4; ++db) {
                bf16x8 vb = *(const bf16x8*)&Vs[(db * 32 + l31) * VST + ks * 16 + hf * 8];
                o_[db] = __builtin_amdgcn_mfma_f32_32x32x16_bf16(pa[ks], vb, o_[db], 0, 0, 0);
            }
        }
        __builtin_amdgcn_s_setprio(0);
    }

    // ---- epilogue: per-row 1/l gather + fp32 store (lanes contiguous in d) ----
    #pragma unroll
    for (int r = 0; r < 16; ++r) {
        const int rq = (r & 3) + 8 * (r >> 2) + 4 * hf;
        const float lr = __shfl(l, rq);
        const float inv = 1.f / lr;
        const int qg = wq0 + rq;
        float* ob = out + (size_t)(b * Sc + qg) * (Hc * Dc) + h * Dc + l31;
        ob[0]  = o_[0][r] * inv;
        ob[32] = o_[1][r] * inv;
        ob[64] = o_[2][r] * inv;
        ob[96] = o_[3][r] * inv;
    }
}

extern "C" void kernel_launch(void* const* d_in, const int* in_sizes, int n_in,
                              void* d_out, int out_size, void* d_ws, size_t ws_size,
                              hipStream_t stream) {
    const float* qkv = (const float*)d_in[0];
    const int* causal = (const int*)d_in[1];
    float* out = (float*)d_out;
    dim3 grid((Sc / BQ) * Bc * Hc);   // 16 * 64 = 1024, 1D balanced mapping
    attn_fwd<<<grid, 256, 0, stream>>>(qkv, causal, out);
}